// Round 9
// baseline (1163.740 us; speedup 1.0000x reference)
//
#include <hip/hip_runtime.h>
#include <stdint.h>

#define M_DIM 8192
#define N_DIM 4096
#define K_DIM 4224
#define BK 64

typedef float f32x16 __attribute__((ext_vector_type(16)));
typedef int   i32x8  __attribute__((ext_vector_type(8)));
typedef int   i32x4  __attribute__((ext_vector_type(4)));

#define RAW_BARRIER()  asm volatile("s_barrier" ::: "memory")
#define WAIT_VM6()     asm volatile("s_waitcnt vmcnt(6)" ::: "memory")
#define WAIT_VM0()     asm volatile("s_waitcnt vmcnt(0)" ::: "memory")

// ---------------------------------------------------------------------------
// fp4(e2m1) nibble + per-16 E8M0 scale -> exact bf8(e5m2), pure VALU.
// ---------------------------------------------------------------------------
__device__ __forceinline__ uint32_t conv4(uint32_t x, uint32_t k1) {
    uint32_t n7   = x & 0x07070707u;
    uint32_t base = __builtin_amdgcn_perm(0x46444240u, 0x3E3C3800u, n7);
    uint32_t nz   = __builtin_amdgcn_perm(0x01010101u, 0x01010100u, n7);
    uint32_t sign = (x & 0x08080808u) << 4;
    return (base + nz * k1 - (nz << 6)) | sign;
}

// 32 elements (2 scale-blocks) per thread; BW-bound (~30us, r5-verified).
__global__ __launch_bounds__(256) void dequant_all(
    const int* __restrict__ Ap, const int* __restrict__ SFA, uint8_t* __restrict__ Aout,
    const int* __restrict__ Bp, const int* __restrict__ SFB, uint8_t* __restrict__ Bout)
{
    const int nhA = M_DIM * K_DIM / 32;
    int i = blockIdx.x * 256 + threadIdx.x;
    const int* p; const int* sf; uint8_t* out; int idx;
    if (i < nhA) { p = Ap; sf = SFA; out = Aout; idx = i; }
    else         { p = Bp; sf = SFB; out = Bout; idx = i - nhA; }

    const int4* p4 = (const int4*)p;
    int4 q0 = p4[4 * idx];
    int4 q1 = p4[4 * idx + 1];
    int4 q2 = p4[4 * idx + 2];
    int4 q3 = p4[4 * idx + 3];
    int2 sfp = ((const int2*)sf)[idx];
    uint32_t k1a = (uint32_t)(((sfp.x - 127) << 2) + 64);
    uint32_t k1b = (uint32_t)(((sfp.y - 127) << 2) + 64);

    uint32_t o[8];
#pragma unroll
    for (int g = 0; g < 4; ++g) {
        int4 pg = (g == 0) ? q0 : (g == 1) ? q1 : (g == 2) ? q2 : q3;
        uint32_t k1 = (g < 2) ? k1a : k1b;
        uint32_t w = (uint32_t)(pg.x & 0xFF) | ((uint32_t)(pg.y & 0xFF) << 8) |
                     ((uint32_t)(pg.z & 0xFF) << 16) | ((uint32_t)pg.w << 24);
        uint32_t lr = conv4(w & 0x0F0F0F0Fu, k1);
        uint32_t hr = conv4((w >> 4) & 0x0F0F0F0Fu, k1);
        o[2 * g]     = __builtin_amdgcn_perm(hr, lr, 0x05010400u); // elems 0..3
        o[2 * g + 1] = __builtin_amdgcn_perm(hr, lr, 0x07030602u); // elems 4..7
    }
    *(uint4*)(out + (size_t)idx * 32)      = make_uint4(o[0], o[1], o[2], o[3]);
    *(uint4*)(out + (size_t)idx * 32 + 16) = make_uint4(o[4], o[5], o[6], o[7]);
}

// ---------------------------------------------------------------------------
// GEMM via MX-scaled MFMA at unity scale: C = scale*(A.B^T) + bias
// Round-8: 512x256 TILE. r1-r7 post-mortems: all schedule/LDS variants
// converge at staged-DMA ~8.0 TB/s (1.08GB/133us; L2/L3-path ceiling —
// FETCH shows HBM only 1.15 TB/s). Only lever left: staged bytes.
// BM=512/BN=256 cuts staging to 830MB (-25%); grid 16x16=256 blocks = 1/CU.
// 8 waves as 4Mx2N, per-wave output 128x128 (acc[4][4]); BK=64.
// LDS: 3 buffers x 48KB = 144KB; stage-ahead-2; per-tile vmcnt(6) keeps the
// newest 6-load stage in flight across the barrier (tile t confirmed by the
// end-of-(t-1) vmcnt(6): only stage(t+1) may remain outstanding).
// Buffer overwrite safe: stage(t+2)->buf[(t+2)%3] holds tile t-1, whose
// reads completed during iter t-1 (lgkm-consumed before its barrier).
// Convoy reads (read-ahead needs 4 bufs = 192KB > 160KB): af0+bf0..3 up
// front, then af[i+1] read under cluster i — ~160cy exposed of ~3500cy/tile.
// ---------------------------------------------------------------------------
__global__ __launch_bounds__(512, 2) void gemm_mx(
    const uint8_t* __restrict__ A, const uint8_t* __restrict__ B,
    const float* __restrict__ scale, const float* __restrict__ bias,
    float* __restrict__ C)
{
    __shared__ uint8_t smem[147456];
    // buf k at offset k*49152: A [512][64] at +0, B [256][64] at +32768

    const int tid  = threadIdx.x;
    const int lane = tid & 63;
    const int w    = tid >> 6;      // 0..7
    const int wm   = w >> 1;        // 0..3 : 128-row band of 512
    const int wn   = w & 1;         // 0..1 : 128-col band of 256
    const int r31  = lane & 31;
    const int h    = lane >> 5;

    // XCD-aware swizzle: 256 blocks, chunk of 32 consecutive per XCD
    const int lin = blockIdx.y * 16 + blockIdx.x;        // gridDim.x == 16
    const int o   = (lin & 7) * 32 + (lin >> 3);         // bijective (256 % 8 == 0)
    const int bn0 = (o & 15) * 256;                      // 16 col-tiles
    const int bm0 = (o >> 4) * 512;                      // 16 row-tiles

    f32x16 acc[4][4];
#pragma unroll
    for (int i = 0; i < 4; ++i)
#pragma unroll
        for (int j = 0; j < 4; ++j)
            acc[i][j] = (f32x16)(0.0f);

    // staging: wave w stages A-rows [w*64, w*64+64) (4 gl_lds of 16 rows) and
    // B-rows [w*32, w*32+32) (2 gl_lds). 6 loads per wave per tile.
    // lane slot = local_row*4 + g''; fetch global granule g = g''^((row>>1)&3)
    // (valid: all row bases 16-aligned => (base+srow)>>1 & 3 == (srow>>1)&3).
    const int srow = lane >> 2;
    const int scol = (((lane & 3) ^ ((lane >> 3) & 3)) << 4);
    const uint8_t* Ag = A + (size_t)(bm0 + w * 64 + srow) * K_DIM + scol;
    const uint8_t* Bg = B + (size_t)(bn0 + w * 32 + srow) * K_DIM + scol;
    uint8_t* Asw = smem + w * 4096;
    uint8_t* Bsw = smem + 32768 + w * 2048;

#define GLDS(gp, lp)                                                             \
    __builtin_amdgcn_global_load_lds(                                            \
        (const __attribute__((address_space(1))) void*)(gp),                     \
        (__attribute__((address_space(3))) void*)(lp), 16, 0, 0)

#define STAGE(koff, boff)                                                        \
    do {                                                                         \
        const uint8_t* ag_ = Ag + (koff);                                        \
        const uint8_t* bg_ = Bg + (koff);                                        \
        GLDS(ag_,                       Asw + (boff));                           \
        GLDS(ag_ + (size_t)16 * K_DIM,  Asw + (boff) + 1024);                    \
        GLDS(ag_ + (size_t)32 * K_DIM,  Asw + (boff) + 2048);                    \
        GLDS(ag_ + (size_t)48 * K_DIM,  Asw + (boff) + 3072);                    \
        GLDS(bg_,                       Bsw + (boff));                           \
        GLDS(bg_ + (size_t)16 * K_DIM,  Bsw + (boff) + 1024);                    \
    } while (0)

    // swizzled, kt-invariant fragment addresses (buf0; bufk = +k*49152)
    const int sx = (r31 >> 1) & 3;
    const uint8_t* pa_lo[4]; const uint8_t* pa_hi[4];
    const uint8_t* pb_lo[4]; const uint8_t* pb_hi[4];
#pragma unroll
    for (int mi = 0; mi < 4; ++mi) {
        const uint8_t* base = smem + (wm * 128 + mi * 32 + r31) * 64;
        pa_lo[mi] = base + (((2 * h)     ^ sx) << 4);
        pa_hi[mi] = base + (((2 * h + 1) ^ sx) << 4);
    }
#pragma unroll
    for (int ni = 0; ni < 4; ++ni) {
        const uint8_t* base = smem + 32768 + (wn * 128 + ni * 32 + r31) * 64;
        pb_lo[ni] = base + (((2 * h)     ^ sx) << 4);
        pb_hi[ni] = base + (((2 * h + 1) ^ sx) << 4);
    }

    i32x8 af[4], bf[4];

    auto rd = [&](const uint8_t* plo, const uint8_t* phi, int off, i32x8& dst) {
        i32x4 lo = *(const i32x4*)(plo + off);
        i32x4 hi = *(const i32x4*)(phi + off);
        dst = __builtin_shufflevector(lo, hi, 0, 1, 2, 3, 4, 5, 6, 7);
    };
    auto mm = [&](const i32x8& a, const i32x8& b, f32x16& c) {
        c = __builtin_amdgcn_mfma_scale_f32_32x32x64_f8f6f4(
                a, b, c, 1, 1, 0, 0x7F7F7F7F, 0, 0x7F7F7F7F);
    };

#define CLUSTER(MI)                                           \
    __builtin_amdgcn_s_setprio(1);                            \
    mm(af[MI], bf[0], acc[MI][0]); mm(af[MI], bf[1], acc[MI][1]); \
    mm(af[MI], bf[2], acc[MI][2]); mm(af[MI], bf[3], acc[MI][3]); \
    __builtin_amdgcn_s_setprio(0);

// convoy compute of the tile in buf at byte offset OB; af[i+1] read under
// cluster i (compiler inserts the fine-grained lgkm waits).
#define CORE(OB)                                              \
    rd(pa_lo[0], pa_hi[0], OB, af[0]);                        \
    rd(pb_lo[0], pb_hi[0], OB, bf[0]);                        \
    rd(pb_lo[1], pb_hi[1], OB, bf[1]);                        \
    rd(pb_lo[2], pb_hi[2], OB, bf[2]);                        \
    rd(pb_lo[3], pb_hi[3], OB, bf[3]);                        \
    CLUSTER(0)                                                \
    rd(pa_lo[1], pa_hi[1], OB, af[1]);                        \
    CLUSTER(1)                                                \
    rd(pa_lo[2], pa_hi[2], OB, af[2]);                        \
    CLUSTER(2)                                                \
    rd(pa_lo[3], pa_hi[3], OB, af[3]);                        \
    CLUSTER(3)

// iter t: stage tile t+2, compute tile t, keep newest stage in flight.
#define BODY(T, OBCUR, OBS)                                   \
    STAGE(((T) + 2) * BK, OBS);                               \
    CORE(OBCUR)                                               \
    WAIT_VM6(); RAW_BARRIER();

    // prologue: stage tiles 0,1 -> buf0,1; vmcnt(6) drains stage(0) only.
    STAGE(0 * BK, 0);
    STAGE(1 * BK, 49152);
    WAIT_VM6();
    RAW_BARRIER();

    // main: t = 0..62, unroll 3 (buf of t = t%3, stage buf = (t+2)%3)
#pragma unroll 1
    for (int g = 0; g < 21; ++g) {
        const int t = 3 * g;
        BODY(t,     0,     98304)
        BODY(t + 1, 49152, 0)
        BODY(t + 2, 98304, 49152)
    }
    // t=63: stage tile 65 -> buf2, compute buf0
    BODY(63, 0, 98304)
    // t=64: no stage; compute buf1; drain stage(65); barrier
    CORE(49152)
    WAIT_VM0(); RAW_BARRIER();
    // t=65: compute buf2 (no more DMA, no barrier)
    CORE(98304)
#undef BODY
#undef CORE
#undef CLUSTER
#undef STAGE
#undef GLDS

    const float sc = scale[0];
#pragma unroll
    for (int ni = 0; ni < 4; ++ni) {
        const int col = bn0 + wn * 128 + ni * 32 + r31;
        const float bv = bias[col];
#pragma unroll
        for (int mi = 0; mi < 4; ++mi) {
            const int rbase = bm0 + wm * 128 + mi * 32 + 4 * h;
#pragma unroll
            for (int reg = 0; reg < 16; ++reg) {
                const int row = rbase + (reg & 3) + 8 * (reg >> 2);
                C[(size_t)row * N_DIM + col] = sc * acc[mi][ni][reg] + bv;
            }
        }
    }
}

extern "C" void kernel_launch(void* const* d_in, const int* in_sizes, int n_in,
                              void* d_out, int out_size, void* d_ws, size_t ws_size,
                              hipStream_t stream) {
    const int*   A_packed = (const int*)d_in[0];
    const int*   SFA      = (const int*)d_in[1];
    const float* scale    = (const float*)d_in[2];
    const int*   B_packed = (const int*)d_in[3];
    const int*   SFB      = (const int*)d_in[4];
    const float* bias     = (const float*)d_in[5];
    float*       out      = (float*)d_out;

    uint8_t* Abf8 = (uint8_t*)d_ws;
    uint8_t* Bbf8 = Abf8 + (size_t)M_DIM * K_DIM;

    const int npairA = M_DIM * K_DIM / 32;  // 1,081,344
    const int npairB = N_DIM * K_DIM / 32;  //   540,672
    dequant_all<<<(npairA + npairB) / 256, 256, 0, stream>>>(
        A_packed, SFA, Abf8, B_packed, SFB, Bbf8);   // 6336 blocks

    dim3 grid(N_DIM / 256, M_DIM / 512);    // (16, 16) = 256 blocks
    gemm_mx<<<grid, 512, 0, stream>>>(Abf8, Bbf8, scale, bias, out);
}